// Round 9
// baseline (38.666 us; speedup 1.0000x reference)
//
#include <hip/hip_runtime.h>
#include <math.h>

#define BATCH 16
#define NKER  16
#define KS    5
#define UNITS 10
#define HIN   28
#define PO    12
#define NPOOL 144
#define NC    25
#define NCELL 2304           // 16*144
#define XSZ   928            // 784 image + zero pad (gated gathers land here)
#define TPAD  28
#define GK    4              // kernels per staging group
#define NGRP  4

// Single dispatch, 16 blocks (one per batch element), 512 threads, ~59KB LDS.
__global__ __launch_bounds__(512, 2) void vdp_one(
    const float* __restrict__ x,       // [B,1,28,28]
    const float* __restrict__ conv_w,  // [K,1,5,5]
    const float* __restrict__ conv_s,  // [K]
    const float* __restrict__ fc_w,    // [2304,10]
    const float* __restrict__ fc_s,    // [10]
    float* __restrict__ out)           // [B*10] p ++ [B*100] sigma_out
{
    const int b = blockIdx.x;
    const int t = threadIdx.x;

    __shared__ float xs[XSZ];                 // 3712 B
    __shared__ float cw[NKER*NC];             // 1600
    __shared__ float sp1[NKER];               // 64
    __shared__ float sp2[UNITS];              // 40
    __shared__ short idx_s[NCELL];            // 4608
    __shared__ float fcw_g[GK*NPOOL*UNITS];   // 23040 (group-local fc_w rows)
    __shared__ float T_s[16][UNITS][TPAD];    // 17920 (partial slots kl*4+q)
    __shared__ float A_s[NKER][UNITS*UNITS];  // 6400
    __shared__ float mu4_s[NKER][UNITS];      // 640
    __shared__ float red_s[8][2];             // 64
    __shared__ float fin_s[12];               // 48: [tr, mn, mu4sum[10]]
    __shared__ float s4[UNITS*UNITS];         // 400
    __shared__ float tmp[UNITS*UNITS];        // 400
    __shared__ float p_s[UNITS], r_s[UNITS], q_s[UNITS];  // 120
    // total ~59,056 B (< 64 KB static limit)

    // ---- staging ----
    {
        const float4* x4 = reinterpret_cast<const float4*>(x + b*HIN*HIN);
        if (t < 196) reinterpret_cast<float4*>(xs)[t] = x4[t];
        if (t >= 196 && t < 196 + (XSZ - 784)) xs[784 + t - 196] = 0.f;
        for (int i = t; i < NKER*NC; i += 512) cw[i] = conv_w[i];
        if (t < NKER) sp1[t] = log1pf(expf(conv_s[t]));
        if (t >= 32 && t < 32 + UNITS) sp2[t-32] = log1pf(expf(fc_s[t-32]));
        // fc_w group 0 -> LDS (coalesced float4 stream)
        const float4* f4 = reinterpret_cast<const float4*>(fc_w);
        float4* d4 = reinterpret_cast<float4*>(fcw_g);
        for (int i = t; i < GK*NPOOL*UNITS/4; i += 512) d4[i] = f4[i];
    }
    __syncthreads();

    // ---- phase 1: conv + relu + argmax-pool (no fc_w!). wave w: k=2w,2w+1 ----
    float v_tr = 0.f, v_mn = 0.f;
    {
        const int wv = t >> 6;
        const int j  = t & 63;
        if (j < 48) {
            #pragma unroll
            for (int kk = 0; kk < 2; ++kk) {
                const int k = 2*wv + kk;
                const float sp1k = sp1[k];
                float cwr[NC];
                #pragma unroll
                for (int c = 0; c < NC; ++c) cwr[c] = cw[k*NC + c];
                #pragma unroll
                for (int ml = 0; ml < 3; ++ml) {
                    const int m  = j + 48*ml;
                    const int pi = m / PO, pj = m - pi*PO;
                    float w6[36];
                    #pragma unroll
                    for (int r = 0; r < 6; ++r)
                        #pragma unroll
                        for (int c2 = 0; c2 < 3; ++c2) {
                            const float2 v2 = *reinterpret_cast<const float2*>(
                                &xs[(2*pi + r)*HIN + 2*pj + 2*c2]);
                            w6[r*6 + 2*c2]     = v2.x;
                            w6[r*6 + 2*c2 + 1] = v2.y;
                        }
                    float a0 = 0.f, a1 = 0.f, a2 = 0.f, a3 = 0.f;
                    #pragma unroll
                    for (int kh = 0; kh < KS; ++kh)
                        #pragma unroll
                        for (int kw = 0; kw < KS; ++kw) {
                            const float w = cwr[kh*KS + kw];
                            a0 = fmaf(w, w6[kh*6 + kw],       a0);
                            a1 = fmaf(w, w6[kh*6 + kw + 1],   a1);
                            a2 = fmaf(w, w6[(kh+1)*6 + kw],   a2);
                            a3 = fmaf(w, w6[(kh+1)*6 + kw+1], a3);
                        }
                    const float r0 = fmaxf(a0, 0.f), r1 = fmaxf(a1, 0.f);
                    const float r2 = fmaxf(a2, 0.f), r3 = fmaxf(a3, 0.f);
                    float bestv = r0; int besta = 0;   // first-max wins (jnp.argmax)
                    if (r1 > bestv) { bestv = r1; besta = 1; }
                    if (r2 > bestv) { bestv = r2; besta = 2; }
                    if (r3 > bestv) { bestv = r3; besta = 3; }
                    const float mu3 = bestv;
                    const float g   = (mu3 > 0.f) ? 1.f : 0.f;

                    float ns = 0.f;                    // ||selected raw patch||^2
                    #pragma unroll
                    for (int kh = 0; kh < KS; ++kh)
                        #pragma unroll
                        for (int kw = 0; kw < KS; ++kw) {
                            const float v0 = w6[kh*6 + kw];
                            const float v1 = w6[kh*6 + kw + 1];
                            const float v2 = w6[(kh+1)*6 + kw];
                            const float v3 = w6[(kh+1)*6 + kw + 1];
                            const float val = (besta < 2) ? ((besta == 0) ? v0 : v1)
                                                          : ((besta == 2) ? v2 : v3);
                            ns = fmaf(val, val, ns);
                        }
                    const int oh = 2*pi + (besta >> 1);
                    const int ow = 2*pj + (besta & 1);
                    idx_s[k*NPOOL + m] = (short)((g > 0.f) ? (oh*HIN + ow) : 784);
                    v_tr = fmaf(g*sp1k, ns, v_tr);
                    v_mn = fmaf(mu3, mu3, v_mn);
                }
            }
        }
    }
    // reduce tr, mn over the block (deterministic)
    {
        float a0 = v_tr, a1 = v_mn;
        #pragma unroll
        for (int off = 32; off >= 1; off >>= 1) {
            a0 += __shfl_down(a0, off);
            a1 += __shfl_down(a1, off);
        }
        if ((t & 63) == 0) { red_s[t >> 6][0] = a0; red_s[t >> 6][1] = a1; }
    }
    __syncthreads();   // idx_s complete; red_s ready
    if (t < 2) {
        float a = 0.f;
        #pragma unroll
        for (int w = 0; w < 8; ++w) a += red_s[w][t];
        fin_s[t] = a;
    }

    // ---- group loop: contract (LDS fcw) -> A + mu4, overlap next staging ----
    for (int g = 0; g < NGRP; ++g) {
        // contraction: T_part[kl*4+q][u][c] over i in [q*36+sub*9, +9)
        {
            const int h   = t >> 5;          // 0..15 half-waves
            const int l   = t & 31;
            const int kl  = h >> 2;          // 0..3
            const int q   = h & 3;           // 0..3
            const int kg  = g*GK + kl;
            const int sub = l & 3;
            const int ch  = (l >> 2) & 3;
            const int uh  = l >> 4;
            const int u0  = uh*5, c0 = ch*7;
            int off_c[7];
            #pragma unroll
            for (int cc = 0; cc < 7; ++cc) {
                const int c = c0 + cc;
                off_c[cc] = (c/KS)*HIN + (c - (c/KS)*KS);
            }
            int idxr[9];
            const int ib  = kg*NPOOL + q*36 + sub*9;
            #pragma unroll
            for (int ii = 0; ii < 9; ++ii) idxr[ii] = idx_s[ib + ii];

            float acc[5][7];
            #pragma unroll
            for (int uu = 0; uu < 5; ++uu)
                #pragma unroll
                for (int cc = 0; cc < 7; ++cc) acc[uu][cc] = 0.f;

            const int rb = (kl*NPOOL + q*36 + sub*9)*UNITS + u0;
            #pragma unroll
            for (int ii = 0; ii < 9; ++ii) {
                float wv[5];
                #pragma unroll
                for (int uu = 0; uu < 5; ++uu) wv[uu] = fcw_g[rb + ii*UNITS + uu];
                float pv[7];
                #pragma unroll
                for (int cc = 0; cc < 7; ++cc) pv[cc] = xs[idxr[ii] + off_c[cc]];
                #pragma unroll
                for (int uu = 0; uu < 5; ++uu)
                    #pragma unroll
                    for (int cc = 0; cc < 7; ++cc)
                        acc[uu][cc] = fmaf(wv[uu], pv[cc], acc[uu][cc]);
            }
            #pragma unroll
            for (int off = 2; off >= 1; off >>= 1)
                #pragma unroll
                for (int uu = 0; uu < 5; ++uu)
                    #pragma unroll
                    for (int cc = 0; cc < 7; ++cc)
                        acc[uu][cc] += __shfl_down(acc[uu][cc], off, 4);
            if (sub == 0)
                #pragma unroll
                for (int uu = 0; uu < 5; ++uu)
                    #pragma unroll
                    for (int cc = 0; cc < 7; ++cc)
                        T_s[kl*4 + q][u0+uu][c0+cc] = acc[uu][cc];
        }
        __syncthreads();

        // A + mu4 (threads < 440) in parallel with next-group staging (wave 7)
        if (t < 400) {
            const int kl = t / 100, uv = t - kl*100;
            const int u = uv / UNITS, v = uv - u*UNITS;
            const int kg = g*GK + kl;
            const int s0 = kl*4;
            float s = 0.f;
            #pragma unroll
            for (int c = 0; c < NC; ++c) {
                const float Tu = T_s[s0][u][c] + T_s[s0+1][u][c]
                               + T_s[s0+2][u][c] + T_s[s0+3][u][c];
                const float Tv = T_s[s0][v][c] + T_s[s0+1][v][c]
                               + T_s[s0+2][v][c] + T_s[s0+3][v][c];
                s = fmaf(Tu, Tv, s);
            }
            A_s[kg][uv] = sp1[kg]*s;
        } else if (t < 440) {
            const int z = t - 400;
            const int kl = z / UNITS, u = z - kl*UNITS;
            const int kg = g*GK + kl;
            const int s0 = kl*4;
            float s = 0.f;
            #pragma unroll
            for (int c = 0; c < NC; ++c) {
                const float Tu = T_s[s0][u][c] + T_s[s0+1][u][c]
                               + T_s[s0+2][u][c] + T_s[s0+3][u][c];
                s = fmaf(cw[kg*NC + c], Tu, s);
            }
            mu4_s[kg][u] = s;     // mu4[u] = sum_k sum_c cw[k,c]*T[k,u,c]
        } else if (t >= 448 && g + 1 < NGRP) {
            const float4* f4 = reinterpret_cast<const float4*>(fc_w + (g+1)*GK*NPOOL*UNITS);
            float4* d4 = reinterpret_cast<float4*>(fcw_g);
            for (int i = t - 448; i < GK*NPOOL*UNITS/4; i += 64) d4[i] = f4[i];
        }
        __syncthreads();
    }

    // ---- finale ----
    if (t < UNITS*UNITS) {
        float a = 0.f;
        #pragma unroll
        for (int k = 0; k < NKER; ++k) a += A_s[k][t];
        const int u = t / UNITS, v = t - u*UNITS;
        if (u == v) a += sp2[u]*(fin_s[0] + fin_s[1]);
        s4[t] = a;
    } else if (t >= 128 && t < 128 + UNITS) {
        const int u = t - 128;
        float a = 0.f;
        #pragma unroll
        for (int k = 0; k < NKER; ++k) a += mu4_s[k][u];
        fin_s[2 + u] = a;
    }
    __syncthreads();
    if (t == 0) {
        float mx = fin_s[2];
        #pragma unroll
        for (int u = 1; u < UNITS; ++u) mx = fmaxf(mx, fin_s[2+u]);
        float sum = 0.f;
        float e[UNITS];
        #pragma unroll
        for (int u = 0; u < UNITS; ++u) { e[u] = expf(fin_s[2+u] - mx); sum += e[u]; }
        #pragma unroll
        for (int u = 0; u < UNITS; ++u) p_s[u] = e[u] / sum;
    }
    __syncthreads();
    if (t < UNITS) {
        float r = 0.f;
        #pragma unroll
        for (int j = 0; j < UNITS; ++j) r = fmaf(p_s[j], s4[j*UNITS + t], r);
        r_s[t] = r;
    }
    __syncthreads();
    if (t < UNITS*UNITS) {
        const int i = t / UNITS, k2 = t - i*UNITS;
        tmp[t] = p_s[i]*(s4[t] - r_s[k2]);
    }
    __syncthreads();
    if (t < UNITS) {
        float q = 0.f;
        #pragma unroll
        for (int kk = 0; kk < UNITS; ++kk) q = fmaf(tmp[t*UNITS + kk], p_s[kk], q);
        q_s[t] = q;
    }
    __syncthreads();
    if (t < UNITS*UNITS) {
        const int i = t / UNITS, l = t - i*UNITS;
        out[BATCH*UNITS + b*UNITS*UNITS + t] = p_s[l]*(tmp[i*UNITS + l] - q_s[i]);
    }
    if (t < UNITS) out[b*UNITS + t] = p_s[t];
}

extern "C" void kernel_launch(void* const* d_in, const int* in_sizes, int n_in,
                              void* d_out, int out_size, void* d_ws, size_t ws_size,
                              hipStream_t stream) {
    const float* x      = (const float*)d_in[0];
    const float* conv_w = (const float*)d_in[1];
    const float* conv_s = (const float*)d_in[2];
    const float* fc_w   = (const float*)d_in[3];
    const float* fc_s   = (const float*)d_in[4];
    float* out = (float*)d_out;
    vdp_one<<<BATCH, 512, 0, stream>>>(x, conv_w, conv_s, fc_w, fc_s, out);
}